// Round 8
// baseline (16.950 us; speedup 1.0000x reference)
//
#include <hip/hip_runtime.h>
#include <math.h>

// field[c,x,y] = sum_n exp(-(x-xc[n])^2/(2s^2)) * exp(-(y-yc[n])^2/(2s^2)) * v[c,n]
// v = init_vectors * (32/(W+L)), s = 32. Output [1,2,W,L] fp32, y fastest.
//
// R7: (1) 32x128 tile, 512-thread blocks, grid 1024 = 4 blocks/CU ->
// 32 waves/CU (max occupancy), preamble per output byte halved, single-pass
// ballot scan; (2) regular (not nontemporal) stores — isolated revert of R5's
// confound; (3) prefetched bump data (branchless min-clamp) so the per-bump
// chain is slab-write -> lgkmcnt(0) -> slab-read -> FMA.
// Wave-synchronous slab sharing (one exp per lane per bump) kept from R6.

#define N_MAX  512
#define TX     32
#define TY     128
#define R_CUT  112.0f

#define EXP2F(x) __builtin_amdgcn_exp2f(x)

typedef float f4 __attribute__((ext_vector_type(4)));

__global__ __launch_bounds__(512, 8) void motion_field_kernel(
    const float* __restrict__ init_vectors,  // [2, N]
    const int*   __restrict__ x_coord,       // [N]
    const int*   __restrict__ y_coord,       // [N]
    const int*   __restrict__ d_width,       // [1]
    const int*   __restrict__ d_lenth,       // [1]
    float*       __restrict__ out,           // [2, W, L]
    int N, int W, int L)
{
    __shared__ float2 s_xy[N_MAX];           // (xc*S, yc*S)
    __shared__ float2 s_v[N_MAX];            // (v0, v1) prescaled
    __shared__ short  s_list[N_MAX];
    __shared__ int    s_cnt[8];
    __shared__ float  s_w[8][2][64];         // per-wave slab [wave][parity][slot]

    const int tid  = threadIdx.x;
    const int wave = tid >> 6;               // 0..7
    const int lane = tid & 63;

    // S = sqrt(log2(e)/(2*32*32)); exp(-d^2/2048) = exp2(-(d*S)^2)
    const float S = 0.02654008814f;
    const float scale = 32.0f / (float)(d_width[0] + d_lenth[0]);  // MAGNITUDE=1

    // stage bump data: one entry per thread (512 threads >= N)
    if (tid < N) {
        s_xy[tid] = make_float2((float)x_coord[tid] * S, (float)y_coord[tid] * S);
        s_v[tid]  = make_float2(init_vectors[tid] * scale,
                                init_vectors[N + tid] * scale);
    }
    __syncthreads();

    const int x0 = blockIdx.x * TX;
    const int y0 = blockIdx.y * TY;
    const float bx_lo = ((float)x0 - R_CUT) * S;
    const float bx_hi = ((float)(x0 + TX - 1) + R_CUT) * S;
    const float by_lo = ((float)y0 - R_CUT) * S;
    const float by_hi = ((float)(y0 + TY - 1) + R_CUT) * S;

    // ---- single-pass ballot scan + deterministic compaction ----
    bool pred = false;
    if (tid < N) {
        const float2 xy = s_xy[tid];
        pred = (xy.x >= bx_lo) && (xy.x <= bx_hi) &&
               (xy.y >= by_lo) && (xy.y <= by_hi);
    }
    const unsigned long long bm = __ballot(pred);
    if (lane == 0) s_cnt[wave] = __popcll(bm);
    __syncthreads();
    int base = 0, total = 0;
    #pragma unroll
    for (int w = 0; w < 8; ++w) {
        const int c = s_cnt[w];
        if (w < wave) base += c;
        total += c;
    }
    if (pred) {
        const int pos = base + __popcll(bm & ((1ULL << lane) - 1ULL));
        s_list[pos] = (short)tid;
    }
    const int M = total;
    __syncthreads();

    // wave sub-patch: 2 waves in x (16 rows) x 4 waves in y (32 px)
    const int wx = wave >> 2;        // 0..1
    const int wy = wave & 3;         // 0..3
    const int u  = lane >> 2;        // 0..15 row within wave patch
    const int vq = lane & 3;         // 0..3  8-px y strip

    // per-lane weight coordinate: lanes 0-15 -> x, lanes 16-47 -> y
    const bool isx = (lane < 16);
    const int  wcoord = isx ? (x0 + wx * 16 + lane)
                            : (y0 + wy * 32 + (lane - 16));
    const float C = (float)wcoord * S;

    float acc0[8], acc1[8];
    #pragma unroll
    for (int j = 0; j < 8; ++j) { acc0[j] = 0.f; acc1[j] = 0.f; }

    float* const slab0 = &s_w[wave][0][0];
    float* const slab1 = &s_w[wave][1][0];

    if (M > 0) {
        int n0 = (int)s_list[0];
        float2 xy_next = s_xy[n0];
        float2 v_next  = s_v[n0];
        for (int m = 0; m < M; ++m) {
            const float2 xy = xy_next;
            const float2 v  = v_next;
            // branchless prefetch of next bump's data
            const int mn = (m + 1 < M) ? (m + 1) : (M - 1);
            const int nn = (int)s_list[mn];
            xy_next = s_xy[nn];
            v_next  = s_v[nn];

            float* const slab = (m & 1) ? slab1 : slab0;
            const float sel = isx ? xy.x : xy.y;
            const float d   = C - sel;
            slab[lane] = EXP2F(-(d * d));
            asm volatile("s_waitcnt lgkmcnt(0)" ::: "memory");

            const float exu = slab[u];
            const f4 eyA = *(const f4*)&slab[16 + vq * 8];
            const f4 eyB = *(const f4*)&slab[16 + vq * 8 + 4];

            const float e0 = exu * v.x;
            const float e1 = exu * v.y;
            const float eys[8] = {eyA.x, eyA.y, eyA.z, eyA.w,
                                  eyB.x, eyB.y, eyB.z, eyB.w};
            #pragma unroll
            for (int j = 0; j < 8; ++j) {
                acc0[j] = fmaf(e0, eys[j], acc0[j]);
                acc1[j] = fmaf(e1, eys[j], acc1[j]);
            }
        }
    }

    // out[c*W*L + x*L + y]; 8 consecutive y per thread, regular f4 stores
    const size_t WL = (size_t)W * (size_t)L;
    const int x  = x0 + wx * 16 + u;
    const int yb = y0 + wy * 32 + vq * 8;
    const size_t off = (size_t)x * (size_t)L + (size_t)yb;
    f4* p0 = (f4*)&out[off];
    f4* p1 = (f4*)&out[WL + off];
    p0[0] = (f4){acc0[0], acc0[1], acc0[2], acc0[3]};
    p0[1] = (f4){acc0[4], acc0[5], acc0[6], acc0[7]};
    p1[0] = (f4){acc1[0], acc1[1], acc1[2], acc1[3]};
    p1[1] = (f4){acc1[4], acc1[5], acc1[6], acc1[7]};
}

extern "C" void kernel_launch(void* const* d_in, const int* in_sizes, int n_in,
                              void* d_out, int out_size, void* d_ws, size_t ws_size,
                              hipStream_t stream) {
    const float* init_vectors = (const float*)d_in[0];
    const int*   x_coord      = (const int*)d_in[1];
    const int*   y_coord      = (const int*)d_in[2];
    const int*   d_width      = (const int*)d_in[3];
    const int*   d_lenth      = (const int*)d_in[4];
    float*       out          = (float*)d_out;

    const int N = in_sizes[1];                 // 512
    const int WL = out_size / 2;
    int W = 1;
    while ((long long)W * (long long)W < (long long)WL) W <<= 1;
    const int L = WL / W;                      // 2048, 2048

    dim3 grid(W / TX, L / TY);                 // 64 x 16 = 1024 blocks
    dim3 block(512);
    hipLaunchKernelGGL(motion_field_kernel, grid, block, 0, stream,
                       init_vectors, x_coord, y_coord, d_width, d_lenth,
                       out, N, W, L);
}